// Round 1
// baseline (1799.702 us; speedup 1.0000x reference)
//
#include <hip/hip_runtime.h>

#define TT 4096

__device__ __forceinline__ float rl(float v, int k) {
  return __int_as_float(__builtin_amdgcn_readlane(__float_as_int(v), k));
}

__global__ __launch_bounds__(64, 1) void gru_seq(
    const float* __restrict__ x, const int* __restrict__ lengths,
    const float* __restrict__ w_ih, const float* __restrict__ w_hh,
    const float* __restrict__ b_ih, const float* __restrict__ b_hh,
    const float* __restrict__ fc_w, const float* __restrict__ fc_b,
    float* __restrict__ out) {
  const int b = blockIdx.x;
  const int l = threadIdx.x;
  const int j = l & 31;
  const int half = l >> 5;
  const int len = lengths[b];

  // per-lane recurrent weight rows (stay in VGPRs; fully unrolled indexing)
  float wr[32], wz[32], wn[32];
#pragma unroll
  for (int k = 0; k < 32; ++k) wr[k] = w_hh[j * 32 + k];
#pragma unroll
  for (int k = 0; k < 32; ++k) wz[k] = w_hh[(32 + j) * 32 + k];
#pragma unroll
  for (int k = 0; k < 32; ++k) wn[k] = w_hh[(64 + j) * 32 + k];

  float wxr[6], wxz[6], wxn[6];
#pragma unroll
  for (int i = 0; i < 6; ++i) wxr[i] = w_ih[j * 6 + i];
#pragma unroll
  for (int i = 0; i < 6; ++i) wxz[i] = w_ih[(32 + j) * 6 + i];
#pragma unroll
  for (int i = 0; i < 6; ++i) wxn[i] = w_ih[(64 + j) * 6 + i];

  const float br  = b_ih[j] + b_hh[j];            // combined r bias
  const float bz  = b_ih[32 + j] + b_hh[32 + j];  // combined z bias
  const float bxn = b_ih[64 + j];                 // n input-bias
  const float bhn = b_hh[64 + j];                 // n hidden-bias (scaled by r)
  const float fcw = fc_w[half * 32 + j];          // half selects output o
  const float fcb = fc_b[half];

  const float* xb = x + (size_t)b * (TT * 6);
  float* ob = out + (size_t)b * (TT * 2);

  float h = 0.0f;  // lane j holds h[j], replicated across halves

  float cx[6], nx[6];
#pragma unroll
  for (int i = 0; i < 6; ++i) cx[i] = xb[i];

  for (int t = 0; t < len; ++t) {
    // prefetch next step's x (wave-uniform address -> scalar loads),
    // one step ahead keeps ~L2 latency off the serial chain
    const int tn = (t + 1 < len) ? (t + 1) : t;
    const float* xp = xb + tn * 6;
#pragma unroll
    for (int i = 0; i < 6; ++i) nx[i] = xp[i];

    // input-gate contributions (independent of h)
    float xr = br, xz = bz, xn = bxn;
#pragma unroll
    for (int i = 0; i < 6; ++i) {
      xr = fmaf(wxr[i], cx[i], xr);
      xz = fmaf(wxz[i], cx[i], xz);
      xn = fmaf(wxn[i], cx[i], xn);
    }

    // broadcast h via readlane (SGPRs), 96-FMA matvec, 2 chains/gate
    float ar0 = 0.f, ar1 = 0.f, az0 = 0.f, az1 = 0.f, an0 = 0.f, an1 = 0.f;
#pragma unroll
    for (int k = 0; k < 16; ++k) {
      const float h0 = rl(h, k);
      const float h1 = rl(h, k + 16);
      ar0 = fmaf(wr[k], h0, ar0);
      az0 = fmaf(wz[k], h0, az0);
      an0 = fmaf(wn[k], h0, an0);
      ar1 = fmaf(wr[k + 16], h1, ar1);
      az1 = fmaf(wz[k + 16], h1, az1);
      an1 = fmaf(wn[k + 16], h1, an1);
    }
    const float sr = xr + (ar0 + ar1);
    const float sz = xz + (az0 + az1);
    const float hn = bhn + (an0 + an1);

    const float r = __builtin_amdgcn_rcpf(1.0f + __expf(-sr));
    const float z = __builtin_amdgcn_rcpf(1.0f + __expf(-sz));
    const float a = xn + r * hn;
    const float e = __expf(-2.0f * a);               // tanh(a) = (1-e)/(1+e)
    const float n = (1.0f - e) * __builtin_amdgcn_rcpf(1.0f + e);
    const float hnew = n + z * (h - n);
    h = hnew;

    // fc projection: reduce within each 32-lane half (off critical path)
    float p = hnew * fcw;
    p += __shfl_xor(p, 1);
    p += __shfl_xor(p, 2);
    p += __shfl_xor(p, 4);
    p += __shfl_xor(p, 8);
    p += __shfl_xor(p, 16);
    if (j == 0) ob[t * 2 + half] = p + fcb;

#pragma unroll
    for (int i = 0; i < 6; ++i) cx[i] = nx[i];
  }

  // t >= len: ys == 0 -> output is fc_b
  const float fb0 = fc_b[0], fb1 = fc_b[1];
  for (int idx = len * 2 + l; idx < TT * 2; idx += 64)
    ob[idx] = (idx & 1) ? fb1 : fb0;
}

extern "C" void kernel_launch(void* const* d_in, const int* in_sizes, int n_in,
                              void* d_out, int out_size, void* d_ws, size_t ws_size,
                              hipStream_t stream) {
  const float* x       = (const float*)d_in[0];
  const int*   lengths = (const int*)d_in[1];
  const float* w_ih    = (const float*)d_in[2];
  const float* w_hh    = (const float*)d_in[3];
  const float* b_ih    = (const float*)d_in[4];
  const float* b_hh    = (const float*)d_in[5];
  const float* fc_w    = (const float*)d_in[6];
  const float* fc_b    = (const float*)d_in[7];
  float* outp = (float*)d_out;

  hipLaunchKernelGGL(gru_seq, dim3(128), dim3(64), 0, stream,
                     x, lengths, w_ih, w_hh, b_ih, b_hh, fc_w, fc_b, outp);
}

// Round 2
// 1485.735 us; speedup vs baseline: 1.2113x; 1.2113x over previous
//
#include <hip/hip_runtime.h>

#define TT 4096
#define BB 128
#define HH 32

__device__ __forceinline__ float bpermf(int idx_bytes, float v) {
  return __int_as_float(__builtin_amdgcn_ds_bpermute(idx_bytes, __float_as_int(v)));
}

// One wave per batch element. Lane l: j = l&31 owns output row j of each gate;
// half = l>>5 selects which 16-wide K-slice this lane accumulates.
// Invariant: every lane's `h` register holds h[l&31] (replicated across halves).
template <bool USE_WS>
__global__ __launch_bounds__(64, 1) void gru_seq(
    const float* __restrict__ x, const int* __restrict__ lengths,
    const float* __restrict__ w_ih, const float* __restrict__ w_hh,
    const float* __restrict__ b_ih, const float* __restrict__ b_hh,
    const float* __restrict__ fc_w, const float* __restrict__ fc_b,
    float* __restrict__ out, float* __restrict__ hbuf) {
  const int b = blockIdx.x;
  const int l = threadIdx.x;
  const int j = l & 31;
  const int half = l >> 5;
  const int ko = half << 4;  // this lane's K-slice origin (0 or 16)
  const int len = lengths[b];

  // 16-wide K-slices of the three gate rows (48 VGPRs total)
  float wr[16], wz[16], wn[16];
#pragma unroll
  for (int k = 0; k < 16; ++k) wr[k] = w_hh[j * 32 + ko + k];
#pragma unroll
  for (int k = 0; k < 16; ++k) wz[k] = w_hh[(32 + j) * 32 + ko + k];
#pragma unroll
  for (int k = 0; k < 16; ++k) wn[k] = w_hh[(64 + j) * 32 + ko + k];

  float wxr[6], wxz[6], wxn[6];
#pragma unroll
  for (int i = 0; i < 6; ++i) wxr[i] = w_ih[j * 6 + i];
#pragma unroll
  for (int i = 0; i < 6; ++i) wxz[i] = w_ih[(32 + j) * 6 + i];
#pragma unroll
  for (int i = 0; i < 6; ++i) wxn[i] = w_ih[(64 + j) * 6 + i];

  const float br  = b_ih[j] + b_hh[j];
  const float bz  = b_ih[32 + j] + b_hh[32 + j];
  const float bxn = b_ih[64 + j];
  const float bhn = b_hh[64 + j];

  // hoisted bpermute byte-indices: broadcast source lane ko+k, and partner lane
  int bidx[16];
#pragma unroll
  for (int k = 0; k < 16; ++k) bidx[k] = (ko + k) << 2;
  const int pidx = (l ^ 32) << 2;

  const float* xb = x + (size_t)b * (TT * 6);
  float* hrow = hbuf + (size_t)b * (TT * HH);
  float* ob = out + (size_t)b * (TT * 2);

  const float fcw = fc_w[half * 32 + j];  // fallback path only
  const float fcb = fc_b[half];

  float h = 0.0f;

  float cx[6], nx[6];
#pragma unroll
  for (int i = 0; i < 6; ++i) cx[i] = xb[i];

  for (int t = 0; t < len; ++t) {
    // prefetch next x one step ahead (wave-uniform address)
    const int tn = (t + 1 < len) ? (t + 1) : t;
    const float* xp = xb + tn * 6;
#pragma unroll
    for (int i = 0; i < 6; ++i) nx[i] = xp[i];

    // input-side gate contributions (independent of h, fills stall slots)
    float xr = br, xz = bz, xn = bxn;
#pragma unroll
    for (int i = 0; i < 6; ++i) {
      xr = fmaf(wxr[i], cx[i], xr);
      xz = fmaf(wxz[i], cx[i], xz);
      xn = fmaf(wxn[i], cx[i], xn);
    }

    // broadcast this half's 16 h values (half0: h[0..15], half1: h[16..31])
    float hbv[16];
#pragma unroll
    for (int k = 0; k < 16; ++k) hbv[k] = bpermf(bidx[k], h);

    // 48 FMAs, six 8-deep chains
    float ar0 = 0.f, ar1 = 0.f, az0 = 0.f, az1 = 0.f, an0 = 0.f, an1 = 0.f;
#pragma unroll
    for (int k = 0; k < 8; ++k) {
      ar0 = fmaf(wr[k], hbv[k], ar0);
      az0 = fmaf(wz[k], hbv[k], az0);
      an0 = fmaf(wn[k], hbv[k], an0);
      ar1 = fmaf(wr[k + 8], hbv[k + 8], ar1);
      az1 = fmaf(wz[k + 8], hbv[k + 8], az1);
      an1 = fmaf(wn[k + 8], hbv[k + 8], an1);
    }
    const float pr = ar0 + ar1, pz = az0 + az1, pn = an0 + an1;
    // cross-half combine: add partner lane's partial
    const float sr = xr + (pr + bpermf(pidx, pr));
    const float sz = xz + (pz + bpermf(pidx, pz));
    const float hn = bhn + (pn + bpermf(pidx, pn));

    const float r = __builtin_amdgcn_rcpf(1.0f + __expf(-sr));
    const float z = __builtin_amdgcn_rcpf(1.0f + __expf(-sz));
    const float a = xn + r * hn;
    const float e = __expf(-2.0f * a);  // tanh(a) = (1-e)/(1+e)
    const float n = (1.0f - e) * __builtin_amdgcn_rcpf(1.0f + e);
    const float hnew = n + z * (h - n);
    h = hnew;

    if constexpr (USE_WS) {
      if (half == 0) hrow[t * HH + j] = hnew;  // fire-and-forget 128B store
    } else {
      float p = hnew * fcw;
      p += __shfl_xor(p, 1);
      p += __shfl_xor(p, 2);
      p += __shfl_xor(p, 4);
      p += __shfl_xor(p, 8);
      p += __shfl_xor(p, 16);
      if (j == 0) ob[t * 2 + half] = p + fcb;
    }

#pragma unroll
    for (int i = 0; i < 6; ++i) cx[i] = nx[i];
  }

  if constexpr (!USE_WS) {
    const float fb0 = fc_b[0], fb1 = fc_b[1];
    for (int idx = len * 2 + l; idx < TT * 2; idx += 64)
      ob[idx] = (idx & 1) ? fb1 : fb0;
  }
}

// out[b,t,:] = (t < len[b]) ? h[b,t,:] @ fc_w^T + fc_b : fc_b
__global__ __launch_bounds__(256) void fc_apply(
    const float* __restrict__ hbuf, const int* __restrict__ lengths,
    const float* __restrict__ fc_w, const float* __restrict__ fc_b,
    float* __restrict__ out) {
  const int idx = blockIdx.x * 256 + threadIdx.x;  // flattened (b,t)
  const int b = idx >> 12;                         // T = 4096
  const int t = idx & (TT - 1);
  const float fb0 = fc_b[0], fb1 = fc_b[1];
  float* op = out + (size_t)idx * 2;
  if (t >= lengths[b]) {
    op[0] = fb0;
    op[1] = fb1;
    return;
  }
  const float4* hp = (const float4*)(hbuf + (size_t)idx * HH);
  const float4* w0 = (const float4*)(fc_w);
  const float4* w1 = (const float4*)(fc_w + HH);
  float o0 = 0.f, o1 = 0.f;
#pragma unroll
  for (int q = 0; q < 8; ++q) {
    const float4 hv = hp[q], a = w0[q], c = w1[q];
    o0 += hv.x * a.x + hv.y * a.y + hv.z * a.z + hv.w * a.w;
    o1 += hv.x * c.x + hv.y * c.y + hv.z * c.z + hv.w * c.w;
  }
  op[0] = o0 + fb0;
  op[1] = o1 + fb1;
}

extern "C" void kernel_launch(void* const* d_in, const int* in_sizes, int n_in,
                              void* d_out, int out_size, void* d_ws, size_t ws_size,
                              hipStream_t stream) {
  const float* x       = (const float*)d_in[0];
  const int*   lengths = (const int*)d_in[1];
  const float* w_ih    = (const float*)d_in[2];
  const float* w_hh    = (const float*)d_in[3];
  const float* b_ih    = (const float*)d_in[4];
  const float* b_hh    = (const float*)d_in[5];
  const float* fc_w    = (const float*)d_in[6];
  const float* fc_b    = (const float*)d_in[7];
  float* outp = (float*)d_out;

  const size_t need = (size_t)BB * TT * HH * sizeof(float);  // 64 MB
  if (ws_size >= need) {
    float* hbuf = (float*)d_ws;
    hipLaunchKernelGGL(gru_seq<true>, dim3(BB), dim3(64), 0, stream,
                       x, lengths, w_ih, w_hh, b_ih, b_hh, fc_w, fc_b, outp, hbuf);
    hipLaunchKernelGGL(fc_apply, dim3((BB * TT) / 256), dim3(256), 0, stream,
                       hbuf, lengths, fc_w, fc_b, outp);
  } else {
    hipLaunchKernelGGL(gru_seq<false>, dim3(BB), dim3(64), 0, stream,
                       x, lengths, w_ih, w_hh, b_ih, b_hh, fc_w, fc_b, outp, nullptr);
  }
}